// Round 5
// baseline (113.149 us; speedup 1.0000x reference)
//
#include <hip/hip_runtime.h>
#include <hip/hip_bf16.h>

// out[n,m] = exp(-(x2[n] + w2[m] - 2*(x.w[:,m]))) + b[m]
// GEMM 36864 x 512 x 128 (bf16 MFMA) + exp epilogue. Memory-bound:
// ideal HBM = 18.9 MB (x) + 75.5 MB (out) ~= 95 MB -> ~15 us floor.
// R4b: r3 structure + VGPR diet (B frags loaded in 2 halves, cap 128 VGPR
// via __launch_bounds__(512,4) -> 2 blocks/CU) + nontemporal x/out.
// (r4 fix: nontemporal builtins need clang ext-vector types, not HIP float4.)

typedef __bf16 bf16x8 __attribute__((ext_vector_type(8)));
typedef float f32x4 __attribute__((ext_vector_type(4)));
typedef unsigned short ushort8_t __attribute__((ext_vector_type(8)));

#define C_DIM 128
#define M_DIM 512
#define BM 32

__device__ __forceinline__ unsigned short f2bf_bits(float f) {
  unsigned int u = __float_as_uint(f);
  u += 0x7fffu + ((u >> 16) & 1u);
  return (unsigned short)(u >> 16);
}

// fragbuf: [s=0..7][ks=0..3][j=0..3][lane=0..63][e=0..7] bf16; element =
// w[ks*32 + (lane>>4)*8 + e][s*64 + j*16 + (lane&15)].
__global__ __launch_bounds__(256)
void prep_w(const float* __restrict__ w,
            unsigned short* __restrict__ fragbuf,
            float* __restrict__ w2) {
  __shared__ float w2p[4][4][2][16];  // [ks][q][jj][fm]
  const int s = blockIdx.x, jh = blockIdx.y;
  const int t = threadIdx.x;
  const int ks = t >> 6, lane = t & 63, q = lane >> 4, fm = lane & 15;
#pragma unroll
  for (int jj = 0; jj < 2; ++jj) {
    const int j = jh * 2 + jj;
    const int col = s * 64 + j * 16 + fm;
    float sq = 0.f;
    ushort8_t p;
#pragma unroll
    for (int e = 0; e < 8; ++e) {
      const float v = w[(ks * 32 + q * 8 + e) * M_DIM + col];
      sq += v * v;
      p[e] = f2bf_bits(v);
    }
    *(ushort8_t*)(fragbuf + (size_t)s * 8192 + ((ks * 4 + j) * 64 + lane) * 8) = p;
    w2p[ks][q][jj][fm] = sq;
  }
  __syncthreads();
  if (t < 32) {
    const int jj = t >> 4, f = t & 15;
    float sum = 0.f;
#pragma unroll
    for (int kk = 0; kk < 4; ++kk)
#pragma unroll
      for (int qq = 0; qq < 4; ++qq) sum += w2p[kk][qq][jj][f];
    w2[s * 64 + (jh * 2 + jj) * 16 + f] = sum;
  }
}

__global__ __launch_bounds__(512, 4)  // cap 128 VGPR -> 2 blocks/CU
void gauss_main(const float* __restrict__ x,
                const unsigned short* __restrict__ fragbuf,
                const float* __restrict__ w2,
                const float* __restrict__ b,
                float* __restrict__ out) {
  __shared__ unsigned short As[BM * 128];  // 8 KB, XOR-swizzled 16-B granules
  __shared__ float x2s[BM];

  const int t = threadIdx.x;
  const int lane = t & 63, wv = t >> 6;
  const int fm = lane & 15, q = lane >> 4;
  const int m0 = blockIdx.x * BM;  // 1152 blocks

  // --- B fragments, first half (ks=0,1): 8 coalesced 16-B L2 loads
  const bf16x8* bp = (const bf16x8*)fragbuf + (size_t)wv * 1024 + lane;
  bf16x8 bfr[2][4];
#pragma unroll
  for (int k2 = 0; k2 < 2; ++k2)
#pragma unroll
    for (int j = 0; j < 4; ++j) bfr[k2][j] = bp[(k2 * 4 + j) * 64];

  float w2r[4], br[4];
#pragma unroll
  for (int j = 0; j < 4; ++j) {
    const int c = wv * 64 + j * 16 + fm;
    w2r[j] = w2[c];
    br[j] = b[c];
  }

  // --- Stage A: 16 B/thread, coalesced nt loads, + fp32 row sumsq
  {
    const int row = t >> 4, g = t & 15;
    const float* src = x + (size_t)(m0 + row) * C_DIM + g * 8;
    const f32x4 f0 = __builtin_nontemporal_load((const f32x4*)src);
    const f32x4 f1 = __builtin_nontemporal_load((const f32x4*)src + 1);
    float s = f0.x * f0.x + f0.y * f0.y + f0.z * f0.z + f0.w * f0.w +
              f1.x * f1.x + f1.y * f1.y + f1.z * f1.z + f1.w * f1.w;
    ushort8_t p;
    p[0] = f2bf_bits(f0.x); p[1] = f2bf_bits(f0.y);
    p[2] = f2bf_bits(f0.z); p[3] = f2bf_bits(f0.w);
    p[4] = f2bf_bits(f1.x); p[5] = f2bf_bits(f1.y);
    p[6] = f2bf_bits(f1.z); p[7] = f2bf_bits(f1.w);
    *(ushort8_t*)(As + row * 128 + (g ^ (row & 7)) * 8) = p;
    s += __shfl_xor(s, 1); s += __shfl_xor(s, 2);
    s += __shfl_xor(s, 4); s += __shfl_xor(s, 8);
    if (fm == 0) x2s[row] = s;
  }
  __syncthreads();  // the ONLY barrier

  // --- K loop, ks = 0,1 (first-half B)
  f32x4 acc[2][4] = {};
#pragma unroll
  for (int ks = 0; ks < 2; ++ks) {
    const int pg = ((ks * 4 + q) ^ (fm & 7)) * 8;
    const bf16x8 a0 = *(const bf16x8*)(As + fm * 128 + pg);
    const bf16x8 a1 = *(const bf16x8*)(As + (16 + fm) * 128 + pg);
#pragma unroll
    for (int j = 0; j < 4; ++j) {
      acc[0][j] = __builtin_amdgcn_mfma_f32_16x16x32_bf16(a0, bfr[ks][j], acc[0][j], 0, 0, 0);
      acc[1][j] = __builtin_amdgcn_mfma_f32_16x16x32_bf16(a1, bfr[ks][j], acc[1][j], 0, 0, 0);
    }
  }

  // pin the split: don't let the compiler hoist half-2 loads above (VGPR cap)
  __builtin_amdgcn_sched_barrier(0);

  // --- B fragments, second half (ks=2,3), reusing the same registers
#pragma unroll
  for (int k2 = 0; k2 < 2; ++k2)
#pragma unroll
    for (int j = 0; j < 4; ++j) bfr[k2][j] = bp[((2 + k2) * 4 + j) * 64];

#pragma unroll
  for (int ks = 2; ks < 4; ++ks) {
    const int pg = ((ks * 4 + q) ^ (fm & 7)) * 8;
    const bf16x8 a0 = *(const bf16x8*)(As + fm * 128 + pg);
    const bf16x8 a1 = *(const bf16x8*)(As + (16 + fm) * 128 + pg);
#pragma unroll
    for (int j = 0; j < 4; ++j) {
      acc[0][j] = __builtin_amdgcn_mfma_f32_16x16x32_bf16(a0, bfr[ks - 2][j], acc[0][j], 0, 0, 0);
      acc[1][j] = __builtin_amdgcn_mfma_f32_16x16x32_bf16(a1, bfr[ks - 2][j], acc[1][j], 0, 0, 0);
    }
  }

  // --- Epilogue: C/D layout col=lane&15, row=(lane>>4)*4+reg; nt stores
  const f32x4 x2lo = *(const f32x4*)(x2s + q * 4);
  const f32x4 x2hi = *(const f32x4*)(x2s + 16 + q * 4);
#pragma unroll
  for (int i = 0; i < 2; ++i) {
    const f32x4 x2v = i ? x2hi : x2lo;
#pragma unroll
    for (int j = 0; j < 4; ++j) {
      float* po = out + (size_t)(m0 + i * 16 + q * 4) * M_DIM + wv * 64 + j * 16 + fm;
      const float w2c = w2r[j], bc = br[j];
#pragma unroll
      for (int reg = 0; reg < 4; ++reg)
        __builtin_nontemporal_store(
            __expf(-(x2v[reg] + w2c - 2.f * acc[i][j][reg])) + bc,
            po + (size_t)reg * M_DIM);
    }
  }
}

extern "C" void kernel_launch(void* const* d_in, const int* in_sizes, int n_in,
                              void* d_out, int out_size, void* d_ws, size_t ws_size,
                              hipStream_t stream) {
  const float* x = (const float*)d_in[0];   // [36864,128]
  const float* w = (const float*)d_in[1];   // [128,512]
  const float* b = (const float*)d_in[2];   // [512]
  float* out = (float*)d_out;               // [36864,512]

  unsigned short* fragbuf = (unsigned short*)d_ws;                 // 128 KiB
  float* w2 = (float*)((char*)d_ws + (size_t)M_DIM * C_DIM * 2);   // +2 KiB

  prep_w<<<dim3(8, 2), dim3(256), 0, stream>>>(w, fragbuf, w2);
  gauss_main<<<dim3(1152), dim3(512), 0, stream>>>(x, fragbuf, w2, b, out);
}

// Round 6
// 103.976 us; speedup vs baseline: 1.0882x; 1.0882x over previous
//
#include <hip/hip_runtime.h>
#include <hip/hip_bf16.h>

// out[n,m] = exp(-(x2[n] + w2[m] - 2*(x.w[:,m]))) + b[m]
// GEMM 36864 x 512 x 128 (bf16 MFMA) + exp epilogue. Memory-bound:
// ideal HBM = 18.9 MB (x) + 75.5 MB (out) ~= 95 MB -> ~15 us floor.
// R6: r3 structure + __launch_bounds__(512,4) ONLY (128-VGPR cap -> 2
// blocks/CU). No sched_barrier (r5 lesson: order-pinning exposed B-load
// latency), no nontemporal (r5 lesson: nt stores defeat L2 write-merge).
// B-frags in two naturally-scheduled halves; w2/b loads moved post-K-loop
// so they are not live through the MFMA phase.

typedef __bf16 bf16x8 __attribute__((ext_vector_type(8)));
typedef float f32x4 __attribute__((ext_vector_type(4)));
typedef unsigned short ushort8_t __attribute__((ext_vector_type(8)));

#define C_DIM 128
#define M_DIM 512
#define BM 32

__device__ __forceinline__ unsigned short f2bf_bits(float f) {
  unsigned int u = __float_as_uint(f);
  u += 0x7fffu + ((u >> 16) & 1u);
  return (unsigned short)(u >> 16);
}

// fragbuf: [s=0..7][ks=0..3][j=0..3][lane=0..63][e=0..7] bf16; element =
// w[ks*32 + (lane>>4)*8 + e][s*64 + j*16 + (lane&15)].
__global__ __launch_bounds__(256)
void prep_w(const float* __restrict__ w,
            unsigned short* __restrict__ fragbuf,
            float* __restrict__ w2) {
  __shared__ float w2p[4][4][2][16];  // [ks][q][jj][fm]
  const int s = blockIdx.x, jh = blockIdx.y;
  const int t = threadIdx.x;
  const int ks = t >> 6, lane = t & 63, q = lane >> 4, fm = lane & 15;
#pragma unroll
  for (int jj = 0; jj < 2; ++jj) {
    const int j = jh * 2 + jj;
    const int col = s * 64 + j * 16 + fm;
    float sq = 0.f;
    ushort8_t p;
#pragma unroll
    for (int e = 0; e < 8; ++e) {
      const float v = w[(ks * 32 + q * 8 + e) * M_DIM + col];
      sq += v * v;
      p[e] = f2bf_bits(v);
    }
    *(ushort8_t*)(fragbuf + (size_t)s * 8192 + ((ks * 4 + j) * 64 + lane) * 8) = p;
    w2p[ks][q][jj][fm] = sq;
  }
  __syncthreads();
  if (t < 32) {
    const int jj = t >> 4, f = t & 15;
    float sum = 0.f;
#pragma unroll
    for (int kk = 0; kk < 4; ++kk)
#pragma unroll
      for (int qq = 0; qq < 4; ++qq) sum += w2p[kk][qq][jj][f];
    w2[s * 64 + (jh * 2 + jj) * 16 + f] = sum;
  }
}

__global__ __launch_bounds__(512, 4)  // cap 128 VGPR -> 2 blocks/CU, 16 waves
void gauss_main(const float* __restrict__ x,
                const unsigned short* __restrict__ fragbuf,
                const float* __restrict__ w2,
                const float* __restrict__ b,
                float* __restrict__ out) {
  __shared__ unsigned short As[BM * 128];  // 8 KB, XOR-swizzled 16-B granules
  __shared__ float x2s[BM];

  const int t = threadIdx.x;
  const int lane = t & 63, wv = t >> 6;
  const int fm = lane & 15, q = lane >> 4;
  const int m0 = blockIdx.x * BM;  // 1152 blocks

  const bf16x8* bp = (const bf16x8*)fragbuf + (size_t)wv * 1024 + lane;

  // --- Stage A: 16 B/thread, coalesced, + fp32 row sumsq
  {
    const int row = t >> 4, g = t & 15;
    const float* src = x + (size_t)(m0 + row) * C_DIM + g * 8;
    const float4 f0 = ((const float4*)src)[0];
    const float4 f1 = ((const float4*)src)[1];
    float s = f0.x * f0.x + f0.y * f0.y + f0.z * f0.z + f0.w * f0.w +
              f1.x * f1.x + f1.y * f1.y + f1.z * f1.z + f1.w * f1.w;
    ushort8_t p;
    p[0] = f2bf_bits(f0.x); p[1] = f2bf_bits(f0.y);
    p[2] = f2bf_bits(f0.z); p[3] = f2bf_bits(f0.w);
    p[4] = f2bf_bits(f1.x); p[5] = f2bf_bits(f1.y);
    p[6] = f2bf_bits(f1.z); p[7] = f2bf_bits(f1.w);
    *(ushort8_t*)(As + row * 128 + (g ^ (row & 7)) * 8) = p;
    s += __shfl_xor(s, 1); s += __shfl_xor(s, 2);
    s += __shfl_xor(s, 4); s += __shfl_xor(s, 8);
    if (fm == 0) x2s[row] = s;
  }
  __syncthreads();  // the ONLY barrier

  f32x4 acc[2][4] = {};

  // --- K loop in two halves; B-frag loads scheduled naturally (no pinning)
#pragma unroll
  for (int half = 0; half < 2; ++half) {
    bf16x8 bfr[2][4];
#pragma unroll
    for (int k2 = 0; k2 < 2; ++k2)
#pragma unroll
      for (int j = 0; j < 4; ++j) bfr[k2][j] = bp[((half * 2 + k2) * 4 + j) * 64];
#pragma unroll
    for (int k2 = 0; k2 < 2; ++k2) {
      const int ks = half * 2 + k2;
      const int pg = ((ks * 4 + q) ^ (fm & 7)) * 8;
      const bf16x8 a0 = *(const bf16x8*)(As + fm * 128 + pg);
      const bf16x8 a1 = *(const bf16x8*)(As + (16 + fm) * 128 + pg);
#pragma unroll
      for (int j = 0; j < 4; ++j) {
        acc[0][j] = __builtin_amdgcn_mfma_f32_16x16x32_bf16(a0, bfr[k2][j], acc[0][j], 0, 0, 0);
        acc[1][j] = __builtin_amdgcn_mfma_f32_16x16x32_bf16(a1, bfr[k2][j], acc[1][j], 0, 0, 0);
      }
    }
  }

  // --- Epilogue-only loads (not live during K-phase): w2/b for 4 columns
  float w2r[4], br[4];
#pragma unroll
  for (int j = 0; j < 4; ++j) {
    const int c = wv * 64 + j * 16 + fm;
    w2r[j] = w2[c];
    br[j] = b[c];
  }

  // --- Epilogue: C/D layout col=lane&15, row=(lane>>4)*4+reg
  const f32x4 x2lo = *(const f32x4*)(x2s + q * 4);
  const f32x4 x2hi = *(const f32x4*)(x2s + 16 + q * 4);
#pragma unroll
  for (int i = 0; i < 2; ++i) {
    const f32x4 x2v = i ? x2hi : x2lo;
#pragma unroll
    for (int j = 0; j < 4; ++j) {
      float* po = out + (size_t)(m0 + i * 16 + q * 4) * M_DIM + wv * 64 + j * 16 + fm;
      const float w2c = w2r[j], bc = br[j];
#pragma unroll
      for (int reg = 0; reg < 4; ++reg)
        po[(size_t)reg * M_DIM] = __expf(-(x2v[reg] + w2c - 2.f * acc[i][j][reg])) + bc;
    }
  }
}

extern "C" void kernel_launch(void* const* d_in, const int* in_sizes, int n_in,
                              void* d_out, int out_size, void* d_ws, size_t ws_size,
                              hipStream_t stream) {
  const float* x = (const float*)d_in[0];   // [36864,128]
  const float* w = (const float*)d_in[1];   // [128,512]
  const float* b = (const float*)d_in[2];   // [512]
  float* out = (float*)d_out;               // [36864,512]

  unsigned short* fragbuf = (unsigned short*)d_ws;                 // 128 KiB
  float* w2 = (float*)((char*)d_ws + (size_t)M_DIM * C_DIM * 2);   // +2 KiB

  prep_w<<<dim3(8, 2), dim3(256), 0, stream>>>(w, fragbuf, w2);
  gauss_main<<<dim3(1152), dim3(512), 0, stream>>>(x, fragbuf, w2, b, out);
}